// Round 1
// 689.805 us; speedup vs baseline: 1.1737x; 1.1737x over previous
//
#include <hip/hip_runtime.h>
#include <math.h>

// Problem constants: T=4, B=4, C=2, H=W=128 (HW=16384), E=256, half=128.
#define HW 16384

typedef __attribute__((ext_vector_type(8))) _Float16 half8;
typedef __attribute__((ext_vector_type(4))) float f32x4;

// ---------------------------------------------------------------------------
// k_reorder2: BN-folded 2-plane fp16 split of (w*sc)*4096 into MFMA-A layout:
// plane[kb 4][tap 9][quad 4][oc 256][j 8], ic = kb*32+q*8+j.  (r7 proven)
// ---------------------------------------------------------------------------
__global__ __launch_bounds__(256)
void k_reorder2(const float* __restrict__ w1, const float* __restrict__ wres,
                const float* __restrict__ g1, const float* __restrict__ b1,
                const float* __restrict__ m1, const float* __restrict__ v1,
                const float* __restrict__ gr, const float* __restrict__ br,
                const float* __restrict__ mr, const float* __restrict__ vr,
                short* __restrict__ whi, short* __restrict__ wmid,
                short* __restrict__ rhi, short* __restrict__ rmid,
                float* __restrict__ bias1, float* __restrict__ biasr) {
    int i = blockIdx.x * 256 + threadIdx.x;
    if (i < 294912) {                 // 256 oc * 128 ic * 9 taps
        int n = i / 1152, rem = i % 1152;
        int ic = rem / 9, tap = rem % 9;
        float sc = g1[n] / sqrtf(v1[n] + 1e-5f);
        float wv = (w1[i] * sc) * 4096.0f;
        _Float16 h = (_Float16)wv;            // RNE
        float r1 = wv - (float)h;
        _Float16 m = (_Float16)r1;
        int kb = ic >> 5, q = (ic >> 3) & 3, j = ic & 7;
        size_t f = ((((size_t)(kb * 9 + tap)) * 4 + q) * 256 + n) * 8 + j;
        whi[f]  = __builtin_bit_cast(short, h);
        wmid[f] = __builtin_bit_cast(short, m);
    }
    if (i < 32768) {                  // 256 oc * 128 ic
        int n = i >> 7, ic = i & 127;
        float sc = gr[n] / sqrtf(vr[n] + 1e-5f);
        float wv = (wres[i] * sc) * 4096.0f;
        _Float16 h = (_Float16)wv;
        float r1 = wv - (float)h;
        _Float16 m = (_Float16)r1;
        int kb = ic >> 5, q = (ic >> 3) & 3, j = ic & 7;
        size_t f = (((size_t)kb * 4 + q) * 256 + n) * 8 + j;
        rhi[f]  = __builtin_bit_cast(short, h);
        rmid[f] = __builtin_bit_cast(short, m);
    }
    if (i < 256) {
        float sc1 = g1[i] / sqrtf(v1[i] + 1e-5f);
        bias1[i] = (b1[i] - m1[i] * sc1) * 4096.0f;
        float scr_ = gr[i] / sqrtf(vr[i] + 1e-5f);
        biasr[i] = (br[i] - mr[i] * scr_) * 4096.0f;
    }
}

// ---------------------------------------------------------------------------
// k_proj (per t): x_in = x[t] + (first ? 0 : x_out);  3x3 conv 2->128 + BN +
// LIF(vp, skip-read at t=0).  Spikes BIT-PACKED: s1t[b][pix][16B record],
// byte icb holds ic icb*8+bit.  (r9-proven body + r10 bit store)
// grid (4,16,16), block 256.
// ---------------------------------------------------------------------------
__global__ __launch_bounds__(256)
void k_proj(const float* __restrict__ xt, const float* __restrict__ xout,
            const float* __restrict__ wp,
            const float* __restrict__ g, const float* __restrict__ bb,
            const float* __restrict__ mm, const float* __restrict__ vv,
            float* __restrict__ vp, unsigned char* __restrict__ s1t, int first) {
    __shared__ float xin[2 * 10 * 36];
    const int tid = threadIdx.x;
    const int b   = blockIdx.z >> 2;
    const int ocq = blockIdx.z & 3;
    const int gy0 = blockIdx.y * 8, gx0 = blockIdx.x * 32;

    for (int i = tid; i < 680; i += 256) {
        int ch = i / 340, rem = i % 340;
        int r = rem / 34, c = rem % 34;
        int gy = gy0 - 1 + r, gx = gx0 - 1 + c;
        float val = 0.f;
        if (gy >= 0 && gy < 128 && gx >= 0 && gx < 128) {
            int idx = ((b * 2 + ch) << 14) + (gy << 7) + gx;
            val = xt[idx];
            if (!first) val += xout[idx];
        }
        xin[(ch * 10 + r) * 36 + c] = val;
    }
    __syncthreads();

    const int prow = tid >> 5, pcol = tid & 31;
    float xw[2][3][3];
#pragma unroll
    for (int ch = 0; ch < 2; ++ch)
#pragma unroll
        for (int ky = 0; ky < 3; ++ky)
#pragma unroll
            for (int kx = 0; kx < 3; ++kx)
                xw[ch][ky][kx] = xin[(ch * 10 + prow + ky) * 36 + pcol + kx];

    const int pix = ((gy0 + prow) << 7) + gx0 + pcol;
    const int oc_beg = ocq * 32;
    unsigned int pk = 0u;
#pragma unroll
    for (int oo = 0; oo < 32; ++oo) {
        const int oc = oc_beg + oo;
        float acc = 0.f;
#pragma unroll
        for (int ch = 0; ch < 2; ++ch)
#pragma unroll
            for (int ky = 0; ky < 3; ++ky)
#pragma unroll
                for (int kx = 0; kx < 3; ++kx)
                    acc = fmaf(wp[((oc * 2 + ch) * 3 + ky) * 3 + kx], xw[ch][ky][kx], acc);
        float sc = g[oc] / sqrtf(vv[oc] + 1e-5f);
        float h  = (acc - mm[oc]) * sc + bb[oc];
        int idx = ((b * 128 + oc) << 14) + pix;
        float v = first ? 0.f : vp[idx];
        v = v + (h - v) * 0.5f;
        bool s = (v >= 1.0f);
        vp[idx] = s ? 0.f : v;
        pk |= (s ? 1u : 0u) << oo;
    }
    *(unsigned int*)(s1t + ((((size_t)b << 14) + pix) << 4) + ocq * 4) = pk;
}

// ---------------------------------------------------------------------------
// k_temp (per t): 3x3 conv 128->2 + BN + LIF(vtm, skip-read at t=0); writes
// x_out spikes (float).  Bit-packed s1 reads, split-K over ic.  (r9/r10 body)
// grid (128 rows, B), block 256.
// ---------------------------------------------------------------------------
__global__ __launch_bounds__(256)
void k_temp(const unsigned char* __restrict__ s1t, const float* __restrict__ wt,
            const float* __restrict__ g, const float* __restrict__ bb,
            const float* __restrict__ mm, const float* __restrict__ vv,
            float* __restrict__ vtm, float* __restrict__ xout, int first) {
    __shared__ unsigned char sl[49152];   // [icb 16][r 3][p 128] * 8B
    __shared__ float wls[2304];
    __shared__ float red[256];
    const int tid = threadIdx.x;
    const int b   = blockIdx.y;
    const int y0  = blockIdx.x;

    for (int i = tid; i < 2304; i += 256) wls[i] = wt[i];

    for (int i = tid; i < 384; i += 256) {     // 3 rows * 128 px, bit-packed
        int r = i >> 7, px = i & 127;
        int gy = y0 - 1 + r;
        uint4 d = make_uint4(0u, 0u, 0u, 0u);
        if (gy >= 0 && gy < 128)
            d = *(const uint4*)(s1t + ((((size_t)b << 14) + (gy << 7) + px) << 4));
        unsigned int bs[4] = {d.x, d.y, d.z, d.w};
#pragma unroll
        for (int icb = 0; icb < 16; ++icb) {
            unsigned int v8 = (bs[icb >> 2] >> ((icb & 3) * 8)) & 0xFFu;
            unsigned int lo = (v8 & 1u) | ((v8 & 2u) << 7) | ((v8 & 4u) << 14) | ((v8 & 8u) << 21);
            unsigned int hi = ((v8 >> 4) & 1u) | ((v8 & 32u) << 3) | ((v8 & 64u) << 10) | ((v8 & 128u) << 17);
            *(uint2*)&sl[(((icb * 3) + r) * 128 + (px ^ (icb & 7))) * 8] = make_uint2(lo, hi);
        }
    }
    __syncthreads();

    const int x = tid & 127, hf = tid >> 7;
    float a0 = 0.f, a1 = 0.f;
#pragma unroll 1
    for (int ii = 0; ii < 8; ++ii) {
        const int icb = hf * 8 + ii;
        int sw = icb & 7;
        const float* w0 = &wls[icb * 72];
        const float* w1_ = &wls[1152 + icb * 72];
#pragma unroll
        for (int dy = 0; dy < 3; ++dy) {
#pragma unroll
            for (int dx = 0; dx < 3; ++dx) {
                int xx = x - 1 + dx;
                if (xx < 0 || xx > 127) continue;
                uint2 d = *(const uint2*)&sl[((icb * 3 + dy) * 128 + (xx ^ sw)) * 8];
                int tap = dy * 3 + dx;
#pragma unroll
                for (int j = 0; j < 4; ++j) {
                    float f0 = (float)((d.x >> (8 * j)) & 0xFFu);
                    float f1 = (float)((d.y >> (8 * j)) & 0xFFu);
                    a0 = fmaf(w0[j * 9 + tap],        f0, a0);
                    a0 = fmaf(w0[(4 + j) * 9 + tap],  f1, a0);
                    a1 = fmaf(w1_[j * 9 + tap],       f0, a1);
                    a1 = fmaf(w1_[(4 + j) * 9 + tap], f1, a1);
                }
            }
        }
    }
    if (hf) { red[x] = a0; red[128 + x] = a1; }
    __syncthreads();
    if (!hf) {
        a0 += red[x]; a1 += red[128 + x];
#pragma unroll
        for (int oc = 0; oc < 2; ++oc) {
            float acc = (oc == 0) ? a0 : a1;
            float sc = g[oc] / sqrtf(vv[oc] + 1e-5f);
            float yv = (acc - mm[oc]) * sc + bb[oc];
            int idx = ((b * 2 + oc) << 14) + (y0 << 7) + x;
            float v = first ? 0.f : vtm[idx];
            v = v + (yv - v) * 0.5f;
            bool s = (v >= 1.0f);
            vtm[idx]  = s ? 0.f : v;
            xout[idx] = s ? 1.0f : 0.f;
        }
    }
}

// ---------------------------------------------------------------------------
// k_fused (ROUND 12): spill elimination.  Per-wave footprint halved (nt=2,
// tile 2x32, grid.y 1024) and the work phase-split so no more than ~150
// VGPR+AGPR are ever live (3-wave/EU budget = 168):
//   phase A: residual 1x1 path for all t (accr+vres live only here; res
//            spikes packed into srb[4] bitmasks, 4 VGPRs)
//   phase B: 3x3 main conv, t INNERMOST with AH/AM hoisted per (kb,tap):
//            weights read ONCE per block (was 4x) -> 4x less L2 weight
//            traffic; only acc[4][2][2] (64 regs) is the big live set
//   phase C: main-path LIF + stores (va live only here)
// MFMA accumulation order per element is IDENTICAL to the r11 kernel
// (kb->tap, AH then AM; res kb 0..3), so output is bit-identical.
// grid (4 oc-tiles, 1024 px-tiles), block 256 = 4 waves.
// ---------------------------------------------------------------------------
__global__ __launch_bounds__(256, 3)
void k_fused(const unsigned char* __restrict__ s1c,
             const short* __restrict__ whi, const short* __restrict__ wmid,
             const short* __restrict__ rhi, const short* __restrict__ rmid,
             const float* __restrict__ bias1, const float* __restrict__ biasr,
             float* __restrict__ out) {
    __shared__ __align__(16) unsigned char bl[8704];   // [t 4][p 136][16B]

    const int tid = threadIdx.x;
    const int oc0 = blockIdx.x * 64;
    const int yb = blockIdx.y;
    const int b = yb >> 8, ry = (yb >> 2) & 63, cx = yb & 3;
    const int gy0 = ry * 2, gx0 = cx * 32;

    const int w   = tid >> 6, l = tid & 63;
    const int q   = l >> 4,  ln = l & 15;
    const int woc = w >> 1,  wpx = w & 1;

    const size_t wofs = ((size_t)q * 256 + oc0 + woc * 32 + ln) * 8;

    int pb[2], po[2];
#pragma unroll
    for (int nt = 0; nt < 2; ++nt) {
        int px = wpx * 32 + nt * 16 + ln;
        int prow = px >> 5, pcol = px & 31;
        pb[nt] = prow * 34 + pcol;                 // halo-tile entry index
        po[nt] = ((gy0 + prow) << 7) + gx0 + pcol; // out pixel offset
    }

    // ---- stage ALL FOUR t's bit tiles (halo 4x34 = 136 records) ----
    for (int cc = tid; cc < 544; cc += 256) {      // 544 = 4t * 136p
        int t = cc / 136, p = cc - t * 136;
        int r = p / 34, c = p - r * 34;
        int gy = gy0 - 1 + r, gx = gx0 - 1 + c;
        uint4 d = make_uint4(0u, 0u, 0u, 0u);
        if (gy >= 0 && gy < 128 && gx >= 0 && gx < 128)
            d = *(const uint4*)(s1c + (size_t)t * 1048576 +
                                ((((size_t)b << 14) + (gy << 7) + gx) << 4));
        *(uint4*)(bl + cc * 16) = d;
    }
    __syncthreads();   // the ONLY barrier

    const float ds_ = 0.000244140625f;   // 2^-12, exact

    // ================= phase A: residual 1x1 path, all t =================
    unsigned int srb[4];
    {
        f32x4 brr[2];
#pragma unroll
        for (int mt = 0; mt < 2; ++mt)
#pragma unroll
            for (int rg = 0; rg < 4; ++rg)
                brr[mt][rg] = biasr[oc0 + woc * 32 + mt * 16 + q * 4 + rg];

        float vres[2][2][4];
#pragma unroll
        for (int nt = 0; nt < 2; ++nt)
#pragma unroll
            for (int mt = 0; mt < 2; ++mt)
#pragma unroll
                for (int rg = 0; rg < 4; ++rg) vres[nt][mt][rg] = 0.f;

#pragma unroll
        for (int t = 0; t < 4; ++t) {
            const unsigned char* blt = bl + t * 2176;
            f32x4 accr[2][2];
#pragma unroll
            for (int nt = 0; nt < 2; ++nt)
#pragma unroll
                for (int mt = 0; mt < 2; ++mt) accr[nt][mt] = brr[mt];

#pragma unroll
            for (int kb = 0; kb < 4; ++kb) {
                half8 B4[2];
#pragma unroll
                for (int nt = 0; nt < 2; ++nt) {
                    unsigned int v8 = blt[(pb[nt] + 35) * 16 + kb * 4 + q]; // center tap
                    uint4 pk;                   // fp16 1.0 = 0x3C00
                    pk.x = ((v8 & 1u)          | ((v8 & 2u)   << 15)) * 0x3C00u;
                    pk.y = (((v8 >> 2) & 1u)   | ((v8 & 8u)   << 13)) * 0x3C00u;
                    pk.z = (((v8 >> 4) & 1u)   | ((v8 & 32u)  << 11)) * 0x3C00u;
                    pk.w = (((v8 >> 6) & 1u)   | ((v8 & 128u) << 9 )) * 0x3C00u;
                    B4[nt] = __builtin_bit_cast(half8, pk);
                }
                half8 RH[2], RM[2];
#pragma unroll
                for (int mt = 0; mt < 2; ++mt) {
                    RH[mt] = *(const half8*)(rhi  + wofs + (size_t)kb * 8192 + mt * 128);
                    RM[mt] = *(const half8*)(rmid + wofs + (size_t)kb * 8192 + mt * 128);
                }
#pragma unroll
                for (int nt = 0; nt < 2; ++nt)
#pragma unroll
                    for (int mt = 0; mt < 2; ++mt) {
                        accr[nt][mt] = __builtin_amdgcn_mfma_f32_16x16x32_f16(RH[mt], B4[nt], accr[nt][mt], 0, 0, 0);
                        accr[nt][mt] = __builtin_amdgcn_mfma_f32_16x16x32_f16(RM[mt], B4[nt], accr[nt][mt], 0, 0, 0);
                    }
            }

            unsigned int sb = 0u;
#pragma unroll
            for (int nt = 0; nt < 2; ++nt)
#pragma unroll
                for (int mt = 0; mt < 2; ++mt)
#pragma unroll
                    for (int rg = 0; rg < 4; ++rg) {
                        float hr = accr[nt][mt][rg] * ds_;
                        float u = vres[nt][mt][rg];
                        u = u + (hr - u) * 0.5f;
                        bool sr_ = (u >= 1.0f);
                        vres[nt][mt][rg] = sr_ ? 0.f : u;
                        sb |= (sr_ ? 1u : 0u) << (mt * 8 + rg * 2 + nt);
                    }
            srb[t] = sb;
        }
    }

    // ============ phase B: 3x3 main conv, t innermost, weights once ============
    f32x4 acc[4][2][2];   // [t][nt][mt]
#pragma unroll
    for (int mt = 0; mt < 2; ++mt)
#pragma unroll
        for (int rg = 0; rg < 4; ++rg) {
            float bv = bias1[oc0 + woc * 32 + mt * 16 + q * 4 + rg];
#pragma unroll
            for (int t = 0; t < 4; ++t)
#pragma unroll
                for (int nt = 0; nt < 2; ++nt) acc[t][nt][mt][rg] = bv;
        }

    const short* bh = whi  + wofs;
    const short* bm = wmid + wofs;
#pragma unroll 1
    for (int kb = 0; kb < 4; ++kb) {
        const int byi = kb * 4 + q;             // spike byte in px record
#pragma unroll
        for (int tap = 0; tap < 9; ++tap) {
            const int ky = tap / 3, kx = tap % 3;
            half8 AH[2], AM[2];
#pragma unroll
            for (int mt = 0; mt < 2; ++mt) {
                AH[mt] = *(const half8*)(bh + mt * 128);
                AM[mt] = *(const half8*)(bm + mt * 128);
            }
#pragma unroll
            for (int t = 0; t < 4; ++t) {
                const unsigned char* blt = bl + t * 2176;
                half8 B4[2];
#pragma unroll
                for (int nt = 0; nt < 2; ++nt) {
                    unsigned int v8 = blt[(pb[nt] + ky * 34 + kx) * 16 + byi];
                    uint4 pk;
                    pk.x = ((v8 & 1u)          | ((v8 & 2u)   << 15)) * 0x3C00u;
                    pk.y = (((v8 >> 2) & 1u)   | ((v8 & 8u)   << 13)) * 0x3C00u;
                    pk.z = (((v8 >> 4) & 1u)   | ((v8 & 32u)  << 11)) * 0x3C00u;
                    pk.w = (((v8 >> 6) & 1u)   | ((v8 & 128u) << 9 )) * 0x3C00u;
                    B4[nt] = __builtin_bit_cast(half8, pk);
                }
#pragma unroll
                for (int nt = 0; nt < 2; ++nt)
#pragma unroll
                    for (int mt = 0; mt < 2; ++mt) {
                        acc[t][nt][mt] = __builtin_amdgcn_mfma_f32_16x16x32_f16(AH[mt], B4[nt], acc[t][nt][mt], 0, 0, 0);
                        acc[t][nt][mt] = __builtin_amdgcn_mfma_f32_16x16x32_f16(AM[mt], B4[nt], acc[t][nt][mt], 0, 0, 0);
                    }
            }
            bh += 8192; bm += 8192;
        }
    }

    // ================= phase C: main-path LIF + stores =================
    float va[2][2][4];
#pragma unroll
    for (int nt = 0; nt < 2; ++nt)
#pragma unroll
        for (int mt = 0; mt < 2; ++mt)
#pragma unroll
            for (int rg = 0; rg < 4; ++rg) va[nt][mt][rg] = 0.f;

#pragma unroll
    for (int t = 0; t < 4; ++t) {
        const size_t tb = ((size_t)((t * 4 + b) * 256 + oc0)) << 14;
#pragma unroll
        for (int mt = 0; mt < 2; ++mt)
#pragma unroll
            for (int rg = 0; rg < 4; ++rg) {
                const size_t ob = tb + ((size_t)(woc * 32 + mt * 16 + q * 4 + rg) << 14);
#pragma unroll
                for (int nt = 0; nt < 2; ++nt) {
                    float ha = acc[t][nt][mt][rg] * ds_;
                    float v = va[nt][mt][rg];
                    v = v + (ha - v) * 0.5f;
                    bool s = (v >= 1.0f);
                    va[nt][mt][rg] = s ? 0.f : v;
                    float sa = s ? 1.f : 0.f;
                    float sr = ((srb[t] >> (mt * 8 + rg * 2 + nt)) & 1u) ? 1.f : 0.f;
                    out[ob + po[nt]] = sa + sr;
                }
            }
    }
}

// ---------------------------------------------------------------------------
// Workspace layout (bytes), total 40,110,080 (well under the proven 69.5MB):
//   s1c(bits) @ 0           4,194,304   [T][B][pix][16B]
//   vp        @ 4,194,304  33,554,432   (t=0 skip-read -> no memset)
//   vtm       @ 37,748,736    524,288   (t=0 skip-read)
//   xout      @ 38,273,024    524,288   (t=0 not read)
//   whi       @ 38,797,312    589,824
//   wmid      @ 39,387,136    589,824
//   rhi       @ 39,976,960     65,536
//   rmid      @ 40,042,496     65,536
//   bias1     @ 40,108,032      1,024
//   biasr     @ 40,109,056      1,024
// ---------------------------------------------------------------------------
extern "C" void kernel_launch(void* const* d_in, const int* in_sizes, int n_in,
                              void* d_out, int out_size, void* d_ws, size_t ws_size,
                              hipStream_t stream) {
    const float* x      = (const float*)d_in[0];
    const float* w_proj = (const float*)d_in[1];
    const float* g0 = (const float*)d_in[2];
    const float* b0 = (const float*)d_in[3];
    const float* m0 = (const float*)d_in[4];
    const float* v0 = (const float*)d_in[5];
    const float* w_temp = (const float*)d_in[6];
    const float* gt = (const float*)d_in[7];
    const float* bt = (const float*)d_in[8];
    const float* mt = (const float*)d_in[9];
    const float* vt = (const float*)d_in[10];
    const float* w1 = (const float*)d_in[11];
    const float* g1 = (const float*)d_in[12];
    const float* b1 = (const float*)d_in[13];
    const float* m1 = (const float*)d_in[14];
    const float* v1 = (const float*)d_in[15];
    const float* w_res = (const float*)d_in[16];
    const float* gr = (const float*)d_in[17];
    const float* br = (const float*)d_in[18];
    const float* mr = (const float*)d_in[19];
    const float* vr = (const float*)d_in[20];

    char* ws = (char*)d_ws;
    unsigned char* s1c = (unsigned char*)ws;
    float* vp    = (float*)(ws + 4194304);
    float* vtm   = (float*)(ws + 37748736);
    float* xout  = (float*)(ws + 38273024);
    short* whi   = (short*)(ws + 38797312);
    short* wmid  = (short*)(ws + 39387136);
    short* rhi   = (short*)(ws + 39976960);
    short* rmid  = (short*)(ws + 40042496);
    float* bias1 = (float*)(ws + 40108032);
    float* biasr = (float*)(ws + 40109056);

    // weight reorder first: independent of stage A, off the critical tail
    k_reorder2<<<dim3(1152), dim3(256), 0, stream>>>(
        w1, w_res, g1, b1, m1, v1, gr, br, mr, vr,
        whi, wmid, rhi, rmid, bias1, biasr);

    for (int t = 0; t < 4; ++t) {
        const float* xt = x + (size_t)t * 131072;
        unsigned char* s1t = s1c + (size_t)t * 1048576;
        k_proj<<<dim3(4, 16, 16), dim3(256), 0, stream>>>(
            xt, xout, w_proj, g0, b0, m0, v0, vp, s1t, t == 0);
        k_temp<<<dim3(128, 4), dim3(256), 0, stream>>>(
            s1t, w_temp, gt, bt, mt, vt, vtm, xout, t == 0);
    }

    k_fused<<<dim3(4, 1024), dim3(256), 0, stream>>>(
        s1c, whi, wmid, rhi, rmid, bias1, biasr, (float*)d_out);
}

// Round 2
// 630.275 us; speedup vs baseline: 1.2845x; 1.0944x over previous
//
#include <hip/hip_runtime.h>
#include <math.h>

// Problem constants: T=4, B=4, C=2, H=W=128 (HW=16384), E=256, half=128.
#define HW 16384

typedef __attribute__((ext_vector_type(8))) _Float16 half8;
typedef __attribute__((ext_vector_type(4))) float f32x4;

// ---------------------------------------------------------------------------
// k_reorder2: BN-folded 2-plane fp16 split of (w*sc)*4096 into MFMA-A layout:
// plane[kb 4][tap 9][quad 4][oc 256][j 8], ic = kb*32+q*8+j.  (r7 proven)
// ---------------------------------------------------------------------------
__global__ __launch_bounds__(256)
void k_reorder2(const float* __restrict__ w1, const float* __restrict__ wres,
                const float* __restrict__ g1, const float* __restrict__ b1,
                const float* __restrict__ m1, const float* __restrict__ v1,
                const float* __restrict__ gr, const float* __restrict__ br,
                const float* __restrict__ mr, const float* __restrict__ vr,
                short* __restrict__ whi, short* __restrict__ wmid,
                short* __restrict__ rhi, short* __restrict__ rmid,
                float* __restrict__ bias1, float* __restrict__ biasr) {
    int i = blockIdx.x * 256 + threadIdx.x;
    if (i < 294912) {                 // 256 oc * 128 ic * 9 taps
        int n = i / 1152, rem = i % 1152;
        int ic = rem / 9, tap = rem % 9;
        float sc = g1[n] / sqrtf(v1[n] + 1e-5f);
        float wv = (w1[i] * sc) * 4096.0f;
        _Float16 h = (_Float16)wv;            // RNE
        float r1 = wv - (float)h;
        _Float16 m = (_Float16)r1;
        int kb = ic >> 5, q = (ic >> 3) & 3, j = ic & 7;
        size_t f = ((((size_t)(kb * 9 + tap)) * 4 + q) * 256 + n) * 8 + j;
        whi[f]  = __builtin_bit_cast(short, h);
        wmid[f] = __builtin_bit_cast(short, m);
    }
    if (i < 32768) {                  // 256 oc * 128 ic
        int n = i >> 7, ic = i & 127;
        float sc = gr[n] / sqrtf(vr[n] + 1e-5f);
        float wv = (wres[i] * sc) * 4096.0f;
        _Float16 h = (_Float16)wv;
        float r1 = wv - (float)h;
        _Float16 m = (_Float16)r1;
        int kb = ic >> 5, q = (ic >> 3) & 3, j = ic & 7;
        size_t f = (((size_t)kb * 4 + q) * 256 + n) * 8 + j;
        rhi[f]  = __builtin_bit_cast(short, h);
        rmid[f] = __builtin_bit_cast(short, m);
    }
    if (i < 256) {
        float sc1 = g1[i] / sqrtf(v1[i] + 1e-5f);
        bias1[i] = (b1[i] - m1[i] * sc1) * 4096.0f;
        float scr_ = gr[i] / sqrtf(vr[i] + 1e-5f);
        biasr[i] = (br[i] - mr[i] * scr_) * 4096.0f;
    }
}

// ---------------------------------------------------------------------------
// k_proj (per t): x_in = x[t] + (first ? 0 : x_out);  3x3 conv 2->128 + BN +
// LIF(vp, skip-read at t=0).  Spikes BIT-PACKED: s1t[b][pix][16B record],
// byte icb holds ic icb*8+bit.  (r9-proven body + r10 bit store)
// grid (4,16,16), block 256.
// ---------------------------------------------------------------------------
__global__ __launch_bounds__(256)
void k_proj(const float* __restrict__ xt, const float* __restrict__ xout,
            const float* __restrict__ wp,
            const float* __restrict__ g, const float* __restrict__ bb,
            const float* __restrict__ mm, const float* __restrict__ vv,
            float* __restrict__ vp, unsigned char* __restrict__ s1t, int first) {
    __shared__ float xin[2 * 10 * 36];
    const int tid = threadIdx.x;
    const int b   = blockIdx.z >> 2;
    const int ocq = blockIdx.z & 3;
    const int gy0 = blockIdx.y * 8, gx0 = blockIdx.x * 32;

    for (int i = tid; i < 680; i += 256) {
        int ch = i / 340, rem = i % 340;
        int r = rem / 34, c = rem % 34;
        int gy = gy0 - 1 + r, gx = gx0 - 1 + c;
        float val = 0.f;
        if (gy >= 0 && gy < 128 && gx >= 0 && gx < 128) {
            int idx = ((b * 2 + ch) << 14) + (gy << 7) + gx;
            val = xt[idx];
            if (!first) val += xout[idx];
        }
        xin[(ch * 10 + r) * 36 + c] = val;
    }
    __syncthreads();

    const int prow = tid >> 5, pcol = tid & 31;
    float xw[2][3][3];
#pragma unroll
    for (int ch = 0; ch < 2; ++ch)
#pragma unroll
        for (int ky = 0; ky < 3; ++ky)
#pragma unroll
            for (int kx = 0; kx < 3; ++kx)
                xw[ch][ky][kx] = xin[(ch * 10 + prow + ky) * 36 + pcol + kx];

    const int pix = ((gy0 + prow) << 7) + gx0 + pcol;
    const int oc_beg = ocq * 32;
    unsigned int pk = 0u;
#pragma unroll
    for (int oo = 0; oo < 32; ++oo) {
        const int oc = oc_beg + oo;
        float acc = 0.f;
#pragma unroll
        for (int ch = 0; ch < 2; ++ch)
#pragma unroll
            for (int ky = 0; ky < 3; ++ky)
#pragma unroll
                for (int kx = 0; kx < 3; ++kx)
                    acc = fmaf(wp[((oc * 2 + ch) * 3 + ky) * 3 + kx], xw[ch][ky][kx], acc);
        float sc = g[oc] / sqrtf(vv[oc] + 1e-5f);
        float h  = (acc - mm[oc]) * sc + bb[oc];
        int idx = ((b * 128 + oc) << 14) + pix;
        float v = first ? 0.f : vp[idx];
        v = v + (h - v) * 0.5f;
        bool s = (v >= 1.0f);
        vp[idx] = s ? 0.f : v;
        pk |= (s ? 1u : 0u) << oo;
    }
    *(unsigned int*)(s1t + ((((size_t)b << 14) + pix) << 4) + ocq * 4) = pk;
}

// ---------------------------------------------------------------------------
// k_temp (per t): 3x3 conv 128->2 + BN + LIF(vtm, skip-read at t=0); writes
// x_out spikes (float).  Bit-packed s1 reads, split-K over ic.  (r9/r10 body)
// grid (128 rows, B), block 256.
// ---------------------------------------------------------------------------
__global__ __launch_bounds__(256)
void k_temp(const unsigned char* __restrict__ s1t, const float* __restrict__ wt,
            const float* __restrict__ g, const float* __restrict__ bb,
            const float* __restrict__ mm, const float* __restrict__ vv,
            float* __restrict__ vtm, float* __restrict__ xout, int first) {
    __shared__ unsigned char sl[49152];   // [icb 16][r 3][p 128] * 8B
    __shared__ float wls[2304];
    __shared__ float red[256];
    const int tid = threadIdx.x;
    const int b   = blockIdx.y;
    const int y0  = blockIdx.x;

    for (int i = tid; i < 2304; i += 256) wls[i] = wt[i];

    for (int i = tid; i < 384; i += 256) {     // 3 rows * 128 px, bit-packed
        int r = i >> 7, px = i & 127;
        int gy = y0 - 1 + r;
        uint4 d = make_uint4(0u, 0u, 0u, 0u);
        if (gy >= 0 && gy < 128)
            d = *(const uint4*)(s1t + ((((size_t)b << 14) + (gy << 7) + px) << 4));
        unsigned int bs[4] = {d.x, d.y, d.z, d.w};
#pragma unroll
        for (int icb = 0; icb < 16; ++icb) {
            unsigned int v8 = (bs[icb >> 2] >> ((icb & 3) * 8)) & 0xFFu;
            unsigned int lo = (v8 & 1u) | ((v8 & 2u) << 7) | ((v8 & 4u) << 14) | ((v8 & 8u) << 21);
            unsigned int hi = ((v8 >> 4) & 1u) | ((v8 & 32u) << 3) | ((v8 & 64u) << 10) | ((v8 & 128u) << 17);
            *(uint2*)&sl[(((icb * 3) + r) * 128 + (px ^ (icb & 7))) * 8] = make_uint2(lo, hi);
        }
    }
    __syncthreads();

    const int x = tid & 127, hf = tid >> 7;
    float a0 = 0.f, a1 = 0.f;
#pragma unroll 1
    for (int ii = 0; ii < 8; ++ii) {
        const int icb = hf * 8 + ii;
        int sw = icb & 7;
        const float* w0 = &wls[icb * 72];
        const float* w1_ = &wls[1152 + icb * 72];
#pragma unroll
        for (int dy = 0; dy < 3; ++dy) {
#pragma unroll
            for (int dx = 0; dx < 3; ++dx) {
                int xx = x - 1 + dx;
                if (xx < 0 || xx > 127) continue;
                uint2 d = *(const uint2*)&sl[((icb * 3 + dy) * 128 + (xx ^ sw)) * 8];
                int tap = dy * 3 + dx;
#pragma unroll
                for (int j = 0; j < 4; ++j) {
                    float f0 = (float)((d.x >> (8 * j)) & 0xFFu);
                    float f1 = (float)((d.y >> (8 * j)) & 0xFFu);
                    a0 = fmaf(w0[j * 9 + tap],        f0, a0);
                    a0 = fmaf(w0[(4 + j) * 9 + tap],  f1, a0);
                    a1 = fmaf(w1_[j * 9 + tap],       f0, a1);
                    a1 = fmaf(w1_[(4 + j) * 9 + tap], f1, a1);
                }
            }
        }
    }
    if (hf) { red[x] = a0; red[128 + x] = a1; }
    __syncthreads();
    if (!hf) {
        a0 += red[x]; a1 += red[128 + x];
#pragma unroll
        for (int oc = 0; oc < 2; ++oc) {
            float acc = (oc == 0) ? a0 : a1;
            float sc = g[oc] / sqrtf(vv[oc] + 1e-5f);
            float yv = (acc - mm[oc]) * sc + bb[oc];
            int idx = ((b * 2 + oc) << 14) + (y0 << 7) + x;
            float v = first ? 0.f : vtm[idx];
            v = v + (yv - v) * 0.5f;
            bool s = (v >= 1.0f);
            vtm[idx]  = s ? 0.f : v;
            xout[idx] = s ? 1.0f : 0.f;
        }
    }
}

// ---------------------------------------------------------------------------
// k_fused (ROUND 13): VALU de-bottleneck.  The r12 inner loop rebuilt each
// fp16 spike fragment from bits PER TAP (288 builds/wave, ~18 VALU ops each)
// -> VALUBusy 68% while MfmaUtil sat at 47%.  Now each kb's spike bits are
// expanded ONCE into an fp16 plane in LDS (amortized over 9 taps):
//   for kb: { expand bl[kb] -> xp[t][px 136][ic 32] (80B padded stride);
//             barrier; for tap { AH/AM once; for t,nt: B4 = ds_read_b128;
//             8 MFMAs } }
// Inner loop is now pure ds_read_b128 + MFMA with immediate offsets; the
// 80B stride gives a bank-balanced 8-cyc b128 read (256 dw / 32 banks).
// Accumulation order per element (kb->tap->hi,mid; t inner; weights read
// once) is IDENTICAL to r12 -> bit-identical output.
// LDS 8.7K bits + 43.5K expanded = 52.2K -> 3 blocks/CU.
// grid (4 oc-tiles, 1024 px-tiles), block 256 = 4 waves.
// ---------------------------------------------------------------------------
__global__ __launch_bounds__(256, 3)
void k_fused(const unsigned char* __restrict__ s1c,
             const short* __restrict__ whi, const short* __restrict__ wmid,
             const short* __restrict__ rhi, const short* __restrict__ rmid,
             const float* __restrict__ bias1, const float* __restrict__ biasr,
             float* __restrict__ out) {
    __shared__ __align__(16) unsigned char bl[8704];    // [t 4][p 136][16B] bits
    __shared__ __align__(16) unsigned char xp[43520];   // [t 4][p 136][80B] fp16

    const int tid = threadIdx.x;
    const int oc0 = blockIdx.x * 64;
    const int yb = blockIdx.y;
    const int b = yb >> 8, ry = (yb >> 2) & 63, cx = yb & 3;
    const int gy0 = ry * 2, gx0 = cx * 32;

    const int w   = tid >> 6, l = tid & 63;
    const int q   = l >> 4,  ln = l & 15;
    const int woc = w >> 1,  wpx = w & 1;

    const size_t wofs = ((size_t)q * 256 + oc0 + woc * 32 + ln) * 8;

    int pb[2], po[2], eb[2];
#pragma unroll
    for (int nt = 0; nt < 2; ++nt) {
        int px = wpx * 32 + nt * 16 + ln;
        int prow = px >> 5, pcol = px & 31;
        pb[nt] = prow * 34 + pcol;                 // halo-tile entry index
        po[nt] = ((gy0 + prow) << 7) + gx0 + pcol; // out pixel offset
        eb[nt] = pb[nt] * 80 + q * 16;             // expanded-plane lane base
    }

    // ---- stage ALL FOUR t's bit tiles (halo 4x34 = 136 records) ----
    for (int cc = tid; cc < 544; cc += 256) {      // 544 = 4t * 136p
        int t = cc / 136, p = cc - t * 136;
        int r = p / 34, c = p - r * 34;
        int gy = gy0 - 1 + r, gx = gx0 - 1 + c;
        uint4 d = make_uint4(0u, 0u, 0u, 0u);
        if (gy >= 0 && gy < 128 && gx >= 0 && gx < 128)
            d = *(const uint4*)(s1c + (size_t)t * 1048576 +
                                ((((size_t)b << 14) + (gy << 7) + gx) << 4));
        *(uint4*)(bl + cc * 16) = d;
    }
    __syncthreads();

    const float ds_ = 0.000244140625f;   // 2^-12, exact

    // ================= phase A: residual 1x1 path, all t =================
    unsigned int srb[4];
    {
        f32x4 brr[2];
#pragma unroll
        for (int mt = 0; mt < 2; ++mt)
#pragma unroll
            for (int rg = 0; rg < 4; ++rg)
                brr[mt][rg] = biasr[oc0 + woc * 32 + mt * 16 + q * 4 + rg];

        float vres[2][2][4];
#pragma unroll
        for (int nt = 0; nt < 2; ++nt)
#pragma unroll
            for (int mt = 0; mt < 2; ++mt)
#pragma unroll
                for (int rg = 0; rg < 4; ++rg) vres[nt][mt][rg] = 0.f;

#pragma unroll
        for (int t = 0; t < 4; ++t) {
            const unsigned char* blt = bl + t * 2176;
            f32x4 accr[2][2];
#pragma unroll
            for (int nt = 0; nt < 2; ++nt)
#pragma unroll
                for (int mt = 0; mt < 2; ++mt) accr[nt][mt] = brr[mt];

#pragma unroll
            for (int kb = 0; kb < 4; ++kb) {
                half8 B4[2];
#pragma unroll
                for (int nt = 0; nt < 2; ++nt) {
                    unsigned int v8 = blt[(pb[nt] + 35) * 16 + kb * 4 + q]; // center tap
                    uint4 pk;                   // fp16 1.0 = 0x3C00
                    pk.x = ((v8 & 1u)          | ((v8 & 2u)   << 15)) * 0x3C00u;
                    pk.y = (((v8 >> 2) & 1u)   | ((v8 & 8u)   << 13)) * 0x3C00u;
                    pk.z = (((v8 >> 4) & 1u)   | ((v8 & 32u)  << 11)) * 0x3C00u;
                    pk.w = (((v8 >> 6) & 1u)   | ((v8 & 128u) << 9 )) * 0x3C00u;
                    B4[nt] = __builtin_bit_cast(half8, pk);
                }
                half8 RH[2], RM[2];
#pragma unroll
                for (int mt = 0; mt < 2; ++mt) {
                    RH[mt] = *(const half8*)(rhi  + wofs + (size_t)kb * 8192 + mt * 128);
                    RM[mt] = *(const half8*)(rmid + wofs + (size_t)kb * 8192 + mt * 128);
                }
#pragma unroll
                for (int nt = 0; nt < 2; ++nt)
#pragma unroll
                    for (int mt = 0; mt < 2; ++mt) {
                        accr[nt][mt] = __builtin_amdgcn_mfma_f32_16x16x32_f16(RH[mt], B4[nt], accr[nt][mt], 0, 0, 0);
                        accr[nt][mt] = __builtin_amdgcn_mfma_f32_16x16x32_f16(RM[mt], B4[nt], accr[nt][mt], 0, 0, 0);
                    }
            }

            unsigned int sb = 0u;
#pragma unroll
            for (int nt = 0; nt < 2; ++nt)
#pragma unroll
                for (int mt = 0; mt < 2; ++mt)
#pragma unroll
                    for (int rg = 0; rg < 4; ++rg) {
                        float hr = accr[nt][mt][rg] * ds_;
                        float u = vres[nt][mt][rg];
                        u = u + (hr - u) * 0.5f;
                        bool sr_ = (u >= 1.0f);
                        vres[nt][mt][rg] = sr_ ? 0.f : u;
                        sb |= (sr_ ? 1u : 0u) << (mt * 8 + rg * 2 + nt);
                    }
            srb[t] = sb;
        }
    }

    // ============ phase B: 3x3 main conv, kb-outer with LDS-expanded B ============
    f32x4 acc[4][2][2];   // [t][nt][mt]
#pragma unroll
    for (int mt = 0; mt < 2; ++mt)
#pragma unroll
        for (int rg = 0; rg < 4; ++rg) {
            float bv = bias1[oc0 + woc * 32 + mt * 16 + q * 4 + rg];
#pragma unroll
            for (int t = 0; t < 4; ++t)
#pragma unroll
                for (int nt = 0; nt < 2; ++nt) acc[t][nt][mt][rg] = bv;
        }

    const short* bh = whi  + wofs;
    const short* bm = wmid + wofs;
#pragma unroll 1
    for (int kb = 0; kb < 4; ++kb) {
        if (kb) __syncthreads();     // xp reads of kb-1 complete
        // expand this kb's spike bits for all 4 t: bl dword -> 32 fp16 (64B)
        for (int cc = tid; cc < 544; cc += 256) {
            unsigned int wd = *(const unsigned int*)(bl + cc * 16 + kb * 4);
            int t = cc / 136, p = cc - t * 136;
            unsigned char* dst = xp + t * 10880 + p * 80;
#pragma unroll
            for (int c2 = 0; c2 < 4; ++c2) {       // byte q of wd -> 16B chunk q
                unsigned int x0 = wd >> (8 * c2);
                uint4 o;
                o.x = ((x0 & 1u)          | ((x0 & 2u)   << 15)) * 0x3C00u;
                o.y = (((x0 >> 2) & 1u)   | ((x0 & 8u)   << 13)) * 0x3C00u;
                o.z = (((x0 >> 4) & 1u)   | ((x0 & 32u)  << 11)) * 0x3C00u;
                o.w = (((x0 >> 6) & 1u)   | ((x0 & 128u) << 9 )) * 0x3C00u;
                *(uint4*)(dst + c2 * 16) = o;
            }
        }
        __syncthreads();

#pragma unroll
        for (int tap = 0; tap < 9; ++tap) {
            const int toff = ((tap / 3) * 34 + (tap % 3)) * 80;
            half8 AH[2], AM[2];
#pragma unroll
            for (int mt = 0; mt < 2; ++mt) {
                AH[mt] = *(const half8*)(bh + mt * 128);
                AM[mt] = *(const half8*)(bm + mt * 128);
            }
#pragma unroll
            for (int t = 0; t < 4; ++t) {
                half8 B4[2];
#pragma unroll
                for (int nt = 0; nt < 2; ++nt)
                    B4[nt] = *(const half8*)(xp + t * 10880 + eb[nt] + toff);
#pragma unroll
                for (int nt = 0; nt < 2; ++nt)
#pragma unroll
                    for (int mt = 0; mt < 2; ++mt) {
                        acc[t][nt][mt] = __builtin_amdgcn_mfma_f32_16x16x32_f16(AH[mt], B4[nt], acc[t][nt][mt], 0, 0, 0);
                        acc[t][nt][mt] = __builtin_amdgcn_mfma_f32_16x16x32_f16(AM[mt], B4[nt], acc[t][nt][mt], 0, 0, 0);
                    }
            }
            bh += 8192; bm += 8192;
        }
    }

    // ================= phase C: main-path LIF + stores =================
    float va[2][2][4];
#pragma unroll
    for (int nt = 0; nt < 2; ++nt)
#pragma unroll
        for (int mt = 0; mt < 2; ++mt)
#pragma unroll
            for (int rg = 0; rg < 4; ++rg) va[nt][mt][rg] = 0.f;

#pragma unroll
    for (int t = 0; t < 4; ++t) {
        const size_t tb = ((size_t)((t * 4 + b) * 256 + oc0)) << 14;
#pragma unroll
        for (int mt = 0; mt < 2; ++mt)
#pragma unroll
            for (int rg = 0; rg < 4; ++rg) {
                const size_t ob = tb + ((size_t)(woc * 32 + mt * 16 + q * 4 + rg) << 14);
#pragma unroll
                for (int nt = 0; nt < 2; ++nt) {
                    float ha = acc[t][nt][mt][rg] * ds_;
                    float v = va[nt][mt][rg];
                    v = v + (ha - v) * 0.5f;
                    bool s = (v >= 1.0f);
                    va[nt][mt][rg] = s ? 0.f : v;
                    float sa = s ? 1.f : 0.f;
                    float sr = ((srb[t] >> (mt * 8 + rg * 2 + nt)) & 1u) ? 1.f : 0.f;
                    out[ob + po[nt]] = sa + sr;
                }
            }
    }
}

// ---------------------------------------------------------------------------
// Workspace layout (bytes), total 40,110,080 (well under the proven 69.5MB):
//   s1c(bits) @ 0           4,194,304   [T][B][pix][16B]
//   vp        @ 4,194,304  33,554,432   (t=0 skip-read -> no memset)
//   vtm       @ 37,748,736    524,288   (t=0 skip-read)
//   xout      @ 38,273,024    524,288   (t=0 not read)
//   whi       @ 38,797,312    589,824
//   wmid      @ 39,387,136    589,824
//   rhi       @ 39,976,960     65,536
//   rmid      @ 40,042,496     65,536
//   bias1     @ 40,108,032      1,024
//   biasr     @ 40,109,056      1,024
// ---------------------------------------------------------------------------
extern "C" void kernel_launch(void* const* d_in, const int* in_sizes, int n_in,
                              void* d_out, int out_size, void* d_ws, size_t ws_size,
                              hipStream_t stream) {
    const float* x      = (const float*)d_in[0];
    const float* w_proj = (const float*)d_in[1];
    const float* g0 = (const float*)d_in[2];
    const float* b0 = (const float*)d_in[3];
    const float* m0 = (const float*)d_in[4];
    const float* v0 = (const float*)d_in[5];
    const float* w_temp = (const float*)d_in[6];
    const float* gt = (const float*)d_in[7];
    const float* bt = (const float*)d_in[8];
    const float* mt = (const float*)d_in[9];
    const float* vt = (const float*)d_in[10];
    const float* w1 = (const float*)d_in[11];
    const float* g1 = (const float*)d_in[12];
    const float* b1 = (const float*)d_in[13];
    const float* m1 = (const float*)d_in[14];
    const float* v1 = (const float*)d_in[15];
    const float* w_res = (const float*)d_in[16];
    const float* gr = (const float*)d_in[17];
    const float* br = (const float*)d_in[18];
    const float* mr = (const float*)d_in[19];
    const float* vr = (const float*)d_in[20];

    char* ws = (char*)d_ws;
    unsigned char* s1c = (unsigned char*)ws;
    float* vp    = (float*)(ws + 4194304);
    float* vtm   = (float*)(ws + 37748736);
    float* xout  = (float*)(ws + 38273024);
    short* whi   = (short*)(ws + 38797312);
    short* wmid  = (short*)(ws + 39387136);
    short* rhi   = (short*)(ws + 39976960);
    short* rmid  = (short*)(ws + 40042496);
    float* bias1 = (float*)(ws + 40108032);
    float* biasr = (float*)(ws + 40109056);

    // weight reorder first: independent of stage A, off the critical tail
    k_reorder2<<<dim3(1152), dim3(256), 0, stream>>>(
        w1, w_res, g1, b1, m1, v1, gr, br, mr, vr,
        whi, wmid, rhi, rmid, bias1, biasr);

    for (int t = 0; t < 4; ++t) {
        const float* xt = x + (size_t)t * 131072;
        unsigned char* s1t = s1c + (size_t)t * 1048576;
        k_proj<<<dim3(4, 16, 16), dim3(256), 0, stream>>>(
            xt, xout, w_proj, g0, b0, m0, v0, vp, s1t, t == 0);
        k_temp<<<dim3(128, 4), dim3(256), 0, stream>>>(
            s1t, w_temp, gt, bt, mt, vt, vtm, xout, t == 0);
    }

    k_fused<<<dim3(4, 1024), dim3(256), 0, stream>>>(
        s1c, whi, wmid, rhi, rmid, bias1, biasr, (float*)d_out);
}

// Round 3
// 618.010 us; speedup vs baseline: 1.3100x; 1.0198x over previous
//
#include <hip/hip_runtime.h>
#include <math.h>

// Problem constants: T=4, B=4, C=2, H=W=128 (HW=16384), E=256, half=128.
#define HW 16384

typedef __attribute__((ext_vector_type(8))) _Float16 half8;
typedef __attribute__((ext_vector_type(4))) float f32x4;

// ---------------------------------------------------------------------------
// k_reorder2: BN-folded 2-plane fp16 split of (w*sc)*4096 into MFMA-A layout:
// plane[kb 4][tap 9][quad 4][oc 256][j 8], ic = kb*32+q*8+j.  (r7 proven)
// r14: also emits psc[128] (proj BN scale) and tsc[2] (temp BN scale) so the
// hot kernels skip per-thread sqrt/div (identical bit values, same expr).
// ---------------------------------------------------------------------------
__global__ __launch_bounds__(256)
void k_reorder2(const float* __restrict__ w1, const float* __restrict__ wres,
                const float* __restrict__ g1, const float* __restrict__ b1,
                const float* __restrict__ m1, const float* __restrict__ v1,
                const float* __restrict__ gr, const float* __restrict__ br,
                const float* __restrict__ mr, const float* __restrict__ vr,
                const float* __restrict__ g0, const float* __restrict__ v0,
                const float* __restrict__ gt, const float* __restrict__ vt,
                short* __restrict__ whi, short* __restrict__ wmid,
                short* __restrict__ rhi, short* __restrict__ rmid,
                float* __restrict__ bias1, float* __restrict__ biasr,
                float* __restrict__ psc, float* __restrict__ tsc) {
    int i = blockIdx.x * 256 + threadIdx.x;
    if (i < 294912) {                 // 256 oc * 128 ic * 9 taps
        int n = i / 1152, rem = i % 1152;
        int ic = rem / 9, tap = rem % 9;
        float sc = g1[n] / sqrtf(v1[n] + 1e-5f);
        float wv = (w1[i] * sc) * 4096.0f;
        _Float16 h = (_Float16)wv;            // RNE
        float r1 = wv - (float)h;
        _Float16 m = (_Float16)r1;
        int kb = ic >> 5, q = (ic >> 3) & 3, j = ic & 7;
        size_t f = ((((size_t)(kb * 9 + tap)) * 4 + q) * 256 + n) * 8 + j;
        whi[f]  = __builtin_bit_cast(short, h);
        wmid[f] = __builtin_bit_cast(short, m);
    }
    if (i < 32768) {                  // 256 oc * 128 ic
        int n = i >> 7, ic = i & 127;
        float sc = gr[n] / sqrtf(vr[n] + 1e-5f);
        float wv = (wres[i] * sc) * 4096.0f;
        _Float16 h = (_Float16)wv;
        float r1 = wv - (float)h;
        _Float16 m = (_Float16)r1;
        int kb = ic >> 5, q = (ic >> 3) & 3, j = ic & 7;
        size_t f = (((size_t)kb * 4 + q) * 256 + n) * 8 + j;
        rhi[f]  = __builtin_bit_cast(short, h);
        rmid[f] = __builtin_bit_cast(short, m);
    }
    if (i < 256) {
        float sc1 = g1[i] / sqrtf(v1[i] + 1e-5f);
        bias1[i] = (b1[i] - m1[i] * sc1) * 4096.0f;
        float scr_ = gr[i] / sqrtf(vr[i] + 1e-5f);
        biasr[i] = (br[i] - mr[i] * scr_) * 4096.0f;
    }
    if (i < 128) psc[i] = g0[i] / sqrtf(v0[i] + 1e-5f);
    if (i < 2)   tsc[i] = gt[i] / sqrtf(vt[i] + 1e-5f);
}

// ---------------------------------------------------------------------------
// k_proj (per t): x_in = x[t] + (first ? 0 : x_out);  3x3 conv 2->128 + BN +
// LIF(vp, skip-read at t=0, skip-WRITE at t=3: vp[3] is never read).
// Spikes BIT-PACKED: s1t[b][pix][16B record], byte icb holds ic icb*8+bit.
// grid (4,16,16), block 256.
// ---------------------------------------------------------------------------
__global__ __launch_bounds__(256)
void k_proj(const float* __restrict__ xt, const float* __restrict__ xout,
            const float* __restrict__ wp,
            const float* __restrict__ psc, const float* __restrict__ bb,
            const float* __restrict__ mm,
            float* __restrict__ vp, unsigned char* __restrict__ s1t,
            int first, int last) {
    __shared__ float xin[2 * 10 * 36];
    const int tid = threadIdx.x;
    const int b   = blockIdx.z >> 2;
    const int ocq = blockIdx.z & 3;
    const int gy0 = blockIdx.y * 8, gx0 = blockIdx.x * 32;

    for (int i = tid; i < 680; i += 256) {
        int ch = i / 340, rem = i % 340;
        int r = rem / 34, c = rem % 34;
        int gy = gy0 - 1 + r, gx = gx0 - 1 + c;
        float val = 0.f;
        if (gy >= 0 && gy < 128 && gx >= 0 && gx < 128) {
            int idx = ((b * 2 + ch) << 14) + (gy << 7) + gx;
            val = xt[idx];
            if (!first) val += xout[idx];
        }
        xin[(ch * 10 + r) * 36 + c] = val;
    }
    __syncthreads();

    const int prow = tid >> 5, pcol = tid & 31;
    float xw[2][3][3];
#pragma unroll
    for (int ch = 0; ch < 2; ++ch)
#pragma unroll
        for (int ky = 0; ky < 3; ++ky)
#pragma unroll
            for (int kx = 0; kx < 3; ++kx)
                xw[ch][ky][kx] = xin[(ch * 10 + prow + ky) * 36 + pcol + kx];

    const int pix = ((gy0 + prow) << 7) + gx0 + pcol;
    const int oc_beg = ocq * 32;
    unsigned int pk = 0u;
#pragma unroll
    for (int oo = 0; oo < 32; ++oo) {
        const int oc = oc_beg + oo;
        float acc = 0.f;
#pragma unroll
        for (int ch = 0; ch < 2; ++ch)
#pragma unroll
            for (int ky = 0; ky < 3; ++ky)
#pragma unroll
                for (int kx = 0; kx < 3; ++kx)
                    acc = fmaf(wp[((oc * 2 + ch) * 3 + ky) * 3 + kx], xw[ch][ky][kx], acc);
        float sc = psc[oc];
        float h  = (acc - mm[oc]) * sc + bb[oc];
        int idx = ((b * 128 + oc) << 14) + pix;
        float v = first ? 0.f : vp[idx];
        v = v + (h - v) * 0.5f;
        bool s = (v >= 1.0f);
        if (!last) vp[idx] = s ? 0.f : v;
        pk |= (s ? 1u : 0u) << oo;
    }
    *(unsigned int*)(s1t + ((((size_t)b << 14) + pix) << 4) + ocq * 4) = pk;
}

// ---------------------------------------------------------------------------
// k_temp (per t=0..2 only; t=3's outputs are never read): 3x3 conv 128->2 +
// BN + LIF(vtm, skip-read at t=0, skip vtm write at t=2); writes x_out
// spikes (float).  Bit-packed s1 reads, split-K over ic.
// grid (128 rows, B), block 256.
// ---------------------------------------------------------------------------
__global__ __launch_bounds__(256)
void k_temp(const unsigned char* __restrict__ s1t, const float* __restrict__ wt,
            const float* __restrict__ tsc, const float* __restrict__ bb,
            const float* __restrict__ mm,
            float* __restrict__ vtm, float* __restrict__ xout,
            int first, int lastv) {
    __shared__ unsigned char sl[49152];   // [icb 16][r 3][p 128] * 8B
    __shared__ float wls[2304];
    __shared__ float red[256];
    const int tid = threadIdx.x;
    const int b   = blockIdx.y;
    const int y0  = blockIdx.x;

    for (int i = tid; i < 2304; i += 256) wls[i] = wt[i];

    for (int i = tid; i < 384; i += 256) {     // 3 rows * 128 px, bit-packed
        int r = i >> 7, px = i & 127;
        int gy = y0 - 1 + r;
        uint4 d = make_uint4(0u, 0u, 0u, 0u);
        if (gy >= 0 && gy < 128)
            d = *(const uint4*)(s1t + ((((size_t)b << 14) + (gy << 7) + px) << 4));
        unsigned int bs[4] = {d.x, d.y, d.z, d.w};
#pragma unroll
        for (int icb = 0; icb < 16; ++icb) {
            unsigned int v8 = (bs[icb >> 2] >> ((icb & 3) * 8)) & 0xFFu;
            unsigned int lo = (v8 & 1u) | ((v8 & 2u) << 7) | ((v8 & 4u) << 14) | ((v8 & 8u) << 21);
            unsigned int hi = ((v8 >> 4) & 1u) | ((v8 & 32u) << 3) | ((v8 & 64u) << 10) | ((v8 & 128u) << 17);
            *(uint2*)&sl[(((icb * 3) + r) * 128 + (px ^ (icb & 7))) * 8] = make_uint2(lo, hi);
        }
    }
    __syncthreads();

    const int x = tid & 127, hf = tid >> 7;
    float a0 = 0.f, a1 = 0.f;
#pragma unroll 1
    for (int ii = 0; ii < 8; ++ii) {
        const int icb = hf * 8 + ii;
        int sw = icb & 7;
        const float* w0 = &wls[icb * 72];
        const float* w1_ = &wls[1152 + icb * 72];
#pragma unroll
        for (int dy = 0; dy < 3; ++dy) {
#pragma unroll
            for (int dx = 0; dx < 3; ++dx) {
                int xx = x - 1 + dx;
                if (xx < 0 || xx > 127) continue;
                uint2 d = *(const uint2*)&sl[((icb * 3 + dy) * 128 + (xx ^ sw)) * 8];
                int tap = dy * 3 + dx;
#pragma unroll
                for (int j = 0; j < 4; ++j) {
                    float f0 = (float)((d.x >> (8 * j)) & 0xFFu);
                    float f1 = (float)((d.y >> (8 * j)) & 0xFFu);
                    a0 = fmaf(w0[j * 9 + tap],        f0, a0);
                    a0 = fmaf(w0[(4 + j) * 9 + tap],  f1, a0);
                    a1 = fmaf(w1_[j * 9 + tap],       f0, a1);
                    a1 = fmaf(w1_[(4 + j) * 9 + tap], f1, a1);
                }
            }
        }
    }
    if (hf) { red[x] = a0; red[128 + x] = a1; }
    __syncthreads();
    if (!hf) {
        a0 += red[x]; a1 += red[128 + x];
#pragma unroll
        for (int oc = 0; oc < 2; ++oc) {
            float acc = (oc == 0) ? a0 : a1;
            float sc = tsc[oc];
            float yv = (acc - mm[oc]) * sc + bb[oc];
            int idx = ((b * 2 + oc) << 14) + (y0 << 7) + x;
            float v = first ? 0.f : vtm[idx];
            v = v + (yv - v) * 0.5f;
            bool s = (v >= 1.0f);
            if (!lastv) vtm[idx] = s ? 0.f : v;
            xout[idx] = s ? 1.0f : 0.f;
        }
    }
}

// ---------------------------------------------------------------------------
// k_fused (ROUND 14): LDS bank-conflict fix.  r13's 80B-padded xp records put
// every b128 read on ~8-way aliased banks (20.8M conflict-cycles).  Now:
//   * xp records are UNPADDED 64B -> each (t,tap,nt) wave read covers the
//     contiguous 1024B window {p*64+q*16 : p in [c,c+16), q in 0..3}
//     (lane-permuted stride-16B = conflict-free, same as linear b128).
//   * expand remapped so lane cc writes chunk cc&3 of record cc>>2: store
//     address xp+cc*16 is exactly lane-contiguous; source bit-dword read is
//     a 4-lane broadcast (2 banks-way, free).
// Bit-expansion formulas and MFMA accumulation order are IDENTICAL to r13
// -> bit-identical output.  LDS 8.7K bits + 34K fp16 = 42.5K -> 3 blocks/CU.
// grid (4 oc-tiles, 1024 px-tiles), block 256 = 4 waves.
// ---------------------------------------------------------------------------
__global__ __launch_bounds__(256, 3)
void k_fused(const unsigned char* __restrict__ s1c,
             const short* __restrict__ whi, const short* __restrict__ wmid,
             const short* __restrict__ rhi, const short* __restrict__ rmid,
             const float* __restrict__ bias1, const float* __restrict__ biasr,
             float* __restrict__ out) {
    __shared__ __align__(16) unsigned char bl[8704];    // [t 4][p 136][16B] bits
    __shared__ __align__(16) unsigned char xp[34816];   // [r 544][64B] fp16

    const int tid = threadIdx.x;
    const int oc0 = blockIdx.x * 64;
    const int yb = blockIdx.y;
    const int b = yb >> 8, ry = (yb >> 2) & 63, cx = yb & 3;
    const int gy0 = ry * 2, gx0 = cx * 32;

    const int w   = tid >> 6, l = tid & 63;
    const int q   = l >> 4,  ln = l & 15;
    const int woc = w >> 1,  wpx = w & 1;

    const size_t wofs = ((size_t)q * 256 + oc0 + woc * 32 + ln) * 8;

    int pb[2], po[2], eb[2];
#pragma unroll
    for (int nt = 0; nt < 2; ++nt) {
        int px = wpx * 32 + nt * 16 + ln;
        int prow = px >> 5, pcol = px & 31;
        pb[nt] = prow * 34 + pcol;                 // halo-tile entry index
        po[nt] = ((gy0 + prow) << 7) + gx0 + pcol; // out pixel offset
        eb[nt] = pb[nt] * 64 + q * 16;             // expanded-plane lane base
    }

    // ---- stage ALL FOUR t's bit tiles (halo 4x34 = 136 records) ----
    for (int cc = tid; cc < 544; cc += 256) {      // 544 = 4t * 136p
        int t = cc / 136, p = cc - t * 136;
        int r = p / 34, c = p - r * 34;
        int gy = gy0 - 1 + r, gx = gx0 - 1 + c;
        uint4 d = make_uint4(0u, 0u, 0u, 0u);
        if (gy >= 0 && gy < 128 && gx >= 0 && gx < 128)
            d = *(const uint4*)(s1c + (size_t)t * 1048576 +
                                ((((size_t)b << 14) + (gy << 7) + gx) << 4));
        *(uint4*)(bl + cc * 16) = d;
    }
    __syncthreads();

    const float ds_ = 0.000244140625f;   // 2^-12, exact

    // ================= phase A: residual 1x1 path, all t =================
    unsigned int srb[4];
    {
        f32x4 brr[2];
#pragma unroll
        for (int mt = 0; mt < 2; ++mt)
#pragma unroll
            for (int rg = 0; rg < 4; ++rg)
                brr[mt][rg] = biasr[oc0 + woc * 32 + mt * 16 + q * 4 + rg];

        float vres[2][2][4];
#pragma unroll
        for (int nt = 0; nt < 2; ++nt)
#pragma unroll
            for (int mt = 0; mt < 2; ++mt)
#pragma unroll
                for (int rg = 0; rg < 4; ++rg) vres[nt][mt][rg] = 0.f;

#pragma unroll
        for (int t = 0; t < 4; ++t) {
            const unsigned char* blt = bl + t * 2176;
            f32x4 accr[2][2];
#pragma unroll
            for (int nt = 0; nt < 2; ++nt)
#pragma unroll
                for (int mt = 0; mt < 2; ++mt) accr[nt][mt] = brr[mt];

#pragma unroll
            for (int kb = 0; kb < 4; ++kb) {
                half8 B4[2];
#pragma unroll
                for (int nt = 0; nt < 2; ++nt) {
                    unsigned int v8 = blt[(pb[nt] + 35) * 16 + kb * 4 + q]; // center tap
                    uint4 pk;                   // fp16 1.0 = 0x3C00
                    pk.x = ((v8 & 1u)          | ((v8 & 2u)   << 15)) * 0x3C00u;
                    pk.y = (((v8 >> 2) & 1u)   | ((v8 & 8u)   << 13)) * 0x3C00u;
                    pk.z = (((v8 >> 4) & 1u)   | ((v8 & 32u)  << 11)) * 0x3C00u;
                    pk.w = (((v8 >> 6) & 1u)   | ((v8 & 128u) << 9 )) * 0x3C00u;
                    B4[nt] = __builtin_bit_cast(half8, pk);
                }
                half8 RH[2], RM[2];
#pragma unroll
                for (int mt = 0; mt < 2; ++mt) {
                    RH[mt] = *(const half8*)(rhi  + wofs + (size_t)kb * 8192 + mt * 128);
                    RM[mt] = *(const half8*)(rmid + wofs + (size_t)kb * 8192 + mt * 128);
                }
#pragma unroll
                for (int nt = 0; nt < 2; ++nt)
#pragma unroll
                    for (int mt = 0; mt < 2; ++mt) {
                        accr[nt][mt] = __builtin_amdgcn_mfma_f32_16x16x32_f16(RH[mt], B4[nt], accr[nt][mt], 0, 0, 0);
                        accr[nt][mt] = __builtin_amdgcn_mfma_f32_16x16x32_f16(RM[mt], B4[nt], accr[nt][mt], 0, 0, 0);
                    }
            }

            unsigned int sb = 0u;
#pragma unroll
            for (int nt = 0; nt < 2; ++nt)
#pragma unroll
                for (int mt = 0; mt < 2; ++mt)
#pragma unroll
                    for (int rg = 0; rg < 4; ++rg) {
                        float hr = accr[nt][mt][rg] * ds_;
                        float u = vres[nt][mt][rg];
                        u = u + (hr - u) * 0.5f;
                        bool sr_ = (u >= 1.0f);
                        vres[nt][mt][rg] = sr_ ? 0.f : u;
                        sb |= (sr_ ? 1u : 0u) << (mt * 8 + rg * 2 + nt);
                    }
            srb[t] = sb;
        }
    }

    // ============ phase B: 3x3 main conv, kb-outer with LDS-expanded B ============
    f32x4 acc[4][2][2];   // [t][nt][mt]
#pragma unroll
    for (int mt = 0; mt < 2; ++mt)
#pragma unroll
        for (int rg = 0; rg < 4; ++rg) {
            float bv = bias1[oc0 + woc * 32 + mt * 16 + q * 4 + rg];
#pragma unroll
            for (int t = 0; t < 4; ++t)
#pragma unroll
                for (int nt = 0; nt < 2; ++nt) acc[t][nt][mt][rg] = bv;
        }

    const short* bh = whi  + wofs;
    const short* bm = wmid + wofs;
#pragma unroll 1
    for (int kb = 0; kb < 4; ++kb) {
        if (kb) __syncthreads();     // xp reads of kb-1 complete
        // expand this kb's spike bits for all 4 t.  Lane cc handles chunk
        // cc&3 of record cc>>2 -> store addr xp+cc*16 is lane-contiguous;
        // the bit-dword read is a 4-lane broadcast.
        for (int cc = tid; cc < 2176; cc += 256) {     // 544 rec * 4 chunks
            int r = cc >> 2, c = cc & 3;
            unsigned int dw = *(const unsigned int*)(bl + r * 16 + kb * 4);
            unsigned int x0 = dw >> (c * 8);
            uint4 o;
            o.x = ((x0 & 1u)          | ((x0 & 2u)   << 15)) * 0x3C00u;
            o.y = (((x0 >> 2) & 1u)   | ((x0 & 8u)   << 13)) * 0x3C00u;
            o.z = (((x0 >> 4) & 1u)   | ((x0 & 32u)  << 11)) * 0x3C00u;
            o.w = (((x0 >> 6) & 1u)   | ((x0 & 128u) << 9 )) * 0x3C00u;
            *(uint4*)(xp + cc * 16) = o;
        }
        __syncthreads();

#pragma unroll
        for (int tap = 0; tap < 9; ++tap) {
            const int toff = ((tap / 3) * 34 + (tap % 3)) * 64;
            half8 AH[2], AM[2];
#pragma unroll
            for (int mt = 0; mt < 2; ++mt) {
                AH[mt] = *(const half8*)(bh + mt * 128);
                AM[mt] = *(const half8*)(bm + mt * 128);
            }
#pragma unroll
            for (int t = 0; t < 4; ++t) {
                half8 B4[2];
#pragma unroll
                for (int nt = 0; nt < 2; ++nt)
                    B4[nt] = *(const half8*)(xp + t * 8704 + eb[nt] + toff);
#pragma unroll
                for (int nt = 0; nt < 2; ++nt)
#pragma unroll
                    for (int mt = 0; mt < 2; ++mt) {
                        acc[t][nt][mt] = __builtin_amdgcn_mfma_f32_16x16x32_f16(AH[mt], B4[nt], acc[t][nt][mt], 0, 0, 0);
                        acc[t][nt][mt] = __builtin_amdgcn_mfma_f32_16x16x32_f16(AM[mt], B4[nt], acc[t][nt][mt], 0, 0, 0);
                    }
            }
            bh += 8192; bm += 8192;
        }
    }

    // ================= phase C: main-path LIF + stores =================
    float va[2][2][4];
#pragma unroll
    for (int nt = 0; nt < 2; ++nt)
#pragma unroll
        for (int mt = 0; mt < 2; ++mt)
#pragma unroll
            for (int rg = 0; rg < 4; ++rg) va[nt][mt][rg] = 0.f;

#pragma unroll
    for (int t = 0; t < 4; ++t) {
        const size_t tb = ((size_t)((t * 4 + b) * 256 + oc0)) << 14;
#pragma unroll
        for (int mt = 0; mt < 2; ++mt)
#pragma unroll
            for (int rg = 0; rg < 4; ++rg) {
                const size_t ob = tb + ((size_t)(woc * 32 + mt * 16 + q * 4 + rg) << 14);
#pragma unroll
                for (int nt = 0; nt < 2; ++nt) {
                    float ha = acc[t][nt][mt][rg] * ds_;
                    float v = va[nt][mt][rg];
                    v = v + (ha - v) * 0.5f;
                    bool s = (v >= 1.0f);
                    va[nt][mt][rg] = s ? 0.f : v;
                    float sa = s ? 1.f : 0.f;
                    float sr = ((srb[t] >> (mt * 8 + rg * 2 + nt)) & 1u) ? 1.f : 0.f;
                    out[ob + po[nt]] = sa + sr;
                }
            }
    }
}

// ---------------------------------------------------------------------------
// Workspace layout (bytes), total 40,110,600 (well under the proven 69.5MB):
//   s1c(bits) @ 0           4,194,304   [T][B][pix][16B]
//   vp        @ 4,194,304  33,554,432   (t=0 skip-read, t=3 skip-write)
//   vtm       @ 37,748,736    524,288   (t=0 skip-read, t=2 skip-write)
//   xout      @ 38,273,024    524,288   (t=0 not read)
//   whi       @ 38,797,312    589,824
//   wmid      @ 39,387,136    589,824
//   rhi       @ 39,976,960     65,536
//   rmid      @ 40,042,496     65,536
//   bias1     @ 40,108,032      1,024
//   biasr     @ 40,109,056      1,024
//   psc       @ 40,110,080        512
//   tsc       @ 40,110,592          8
// ---------------------------------------------------------------------------
extern "C" void kernel_launch(void* const* d_in, const int* in_sizes, int n_in,
                              void* d_out, int out_size, void* d_ws, size_t ws_size,
                              hipStream_t stream) {
    const float* x      = (const float*)d_in[0];
    const float* w_proj = (const float*)d_in[1];
    const float* g0 = (const float*)d_in[2];
    const float* b0 = (const float*)d_in[3];
    const float* m0 = (const float*)d_in[4];
    const float* v0 = (const float*)d_in[5];
    const float* w_temp = (const float*)d_in[6];
    const float* gt = (const float*)d_in[7];
    const float* bt = (const float*)d_in[8];
    const float* mt = (const float*)d_in[9];
    const float* vt = (const float*)d_in[10];
    const float* w1 = (const float*)d_in[11];
    const float* g1 = (const float*)d_in[12];
    const float* b1 = (const float*)d_in[13];
    const float* m1 = (const float*)d_in[14];
    const float* v1 = (const float*)d_in[15];
    const float* w_res = (const float*)d_in[16];
    const float* gr = (const float*)d_in[17];
    const float* br = (const float*)d_in[18];
    const float* mr = (const float*)d_in[19];
    const float* vr = (const float*)d_in[20];

    char* ws = (char*)d_ws;
    unsigned char* s1c = (unsigned char*)ws;
    float* vp    = (float*)(ws + 4194304);
    float* vtm   = (float*)(ws + 37748736);
    float* xout  = (float*)(ws + 38273024);
    short* whi   = (short*)(ws + 38797312);
    short* wmid  = (short*)(ws + 39387136);
    short* rhi   = (short*)(ws + 39976960);
    short* rmid  = (short*)(ws + 40042496);
    float* bias1 = (float*)(ws + 40108032);
    float* biasr = (float*)(ws + 40109056);
    float* psc   = (float*)(ws + 40110080);
    float* tsc   = (float*)(ws + 40110592);

    // weight reorder first: independent of stage A, off the critical tail
    k_reorder2<<<dim3(1152), dim3(256), 0, stream>>>(
        w1, w_res, g1, b1, m1, v1, gr, br, mr, vr, g0, v0, gt, vt,
        whi, wmid, rhi, rmid, bias1, biasr, psc, tsc);

    for (int t = 0; t < 4; ++t) {
        const float* xt = x + (size_t)t * 131072;
        unsigned char* s1t = s1c + (size_t)t * 1048576;
        k_proj<<<dim3(4, 16, 16), dim3(256), 0, stream>>>(
            xt, xout, w_proj, psc, b0, m0, vp, s1t, t == 0, t == 3);
        if (t < 3)   // t=3's vtm/xout are never read -> launch is dead work
            k_temp<<<dim3(128, 4), dim3(256), 0, stream>>>(
                s1t, w_temp, tsc, bt, mt, vtm, xout, t == 0, t == 2);
    }

    k_fused<<<dim3(4, 1024), dim3(256), 0, stream>>>(
        s1c, whi, wmid, rhi, rmid, bias1, biasr, (float*)d_out);
}